// Round 1
// baseline (603.444 us; speedup 1.0000x reference)
//
#include <hip/hip_runtime.h>
#include <hip/hip_bf16.h>

// Problem constants
#define S_LEN 1024
#define HID   4096
#define NH    32
#define NKV   8
#define HD    128
#define MIN_IDX 4
#define AO_COLS 4096        // NH*HD
#define HEAD_STRIDE 131072  // S_LEN*HD

typedef __attribute__((ext_vector_type(8))) short short8;
typedef __attribute__((ext_vector_type(4))) float f32x4;

__device__ __forceinline__ unsigned short f2bf(float f) {
  union { float f; unsigned u; } v; v.f = f;
  unsigned r = v.u + 0x7FFFu + ((v.u >> 16) & 1u);   // RNE
  return (unsigned short)(r >> 16);
}
__device__ __forceinline__ float bf2f(unsigned short h) {
  union { unsigned u; float f; } v; v.u = ((unsigned)h) << 16;
  return v.f;
}
__device__ __forceinline__ unsigned pk2(float a, float b) {
  union { __hip_bfloat162 h; unsigned u; } c;
  c.h = __float22bfloat162_rn(make_float2(a, b));    // v_cvt_pk_bf16_f32
  return c.u;
}
__device__ __forceinline__ short8 pack8(float4 a, float4 b) {
  union { short8 s; unsigned u[4]; } r;
  r.u[0] = pk2(a.x, a.y); r.u[1] = pk2(a.z, a.w);
  r.u[2] = pk2(b.x, b.y); r.u[3] = pk2(b.z, b.w);
  return r.s;
}
// float -> order-preserving uint, and inverse
__device__ __forceinline__ unsigned ordf(float f) {
  union { float f; int i; } v; v.f = f;
  return (unsigned)(v.i ^ ((v.i >> 31) | 0x80000000));
}
__device__ __forceinline__ float iordf(unsigned u) {
  union { int i; float f; } v;
  v.i = (u & 0x80000000u) ? (int)(u ^ 0x80000000u) : (int)~u;
  return v.f;
}
__device__ __forceinline__ float wave_sum_f(float v) {
  #pragma unroll
  for (int m = 32; m >= 1; m >>= 1) v += __shfl_xor(v, m);
  return v;
}
__device__ __forceinline__ unsigned wave_max_u(unsigned v) {
  #pragma unroll
  for (int m = 32; m >= 1; m >>= 1) { unsigned o = __shfl_xor(v, m); v = o > v ? o : v; }
  return v;
}
__device__ __forceinline__ unsigned wave_and_u(unsigned v) {
  #pragma unroll
  for (int m = 32; m >= 1; m >>= 1) v &= __shfl_xor(v, m);
  return v;
}
__device__ __forceinline__ unsigned wave_or_u(unsigned v) {
  #pragma unroll
  for (int m = 32; m >= 1; m >>= 1) v |= __shfl_xor(v, m);
  return v;
}
// async global->LDS, 16 B per lane. LDS dest: wave-uniform base + lane*16.
__device__ __forceinline__ void gload_lds16(const unsigned short* g, unsigned short* l) {
  auto gp = (const __attribute__((address_space(1))) unsigned*)g;
  auto lp = (__attribute__((address_space(3))) unsigned*)(unsigned)(unsigned long long)l;
  __builtin_amdgcn_global_load_lds(gp, lp, 16, 0, 0);
}

// ---------------------------------------------------------------------------
// Kernel 0: fp32 -> bf16 convert (8 elems/thread). n must be multiple of 2048.
// ---------------------------------------------------------------------------
__global__ __launch_bounds__(256) void cvt_k(
    const float* __restrict__ src, unsigned short* __restrict__ dst)
{
  const size_t i = ((size_t)blockIdx.x * 256 + threadIdx.x) * 8;
  float4 a = *(const float4*)(src + i);
  float4 b = *(const float4*)(src + i + 4);
  *(short8*)(dst + i) = pack8(a, b);
}

// ---------------------------------------------------------------------------
// Kernel 1: QKV projection (NT gemm, all-bf16, m97-style global_load_lds).
// ---------------------------------------------------------------------------
__global__ __launch_bounds__(256) void gemm_qkv_k(
    const unsigned short* __restrict__ Xb, const unsigned short* __restrict__ Wb,
    unsigned short* __restrict__ Qraw, unsigned short* __restrict__ Kraw,
    unsigned short* __restrict__ Vt)
{
  __shared__ unsigned short As[128 * 32];  // unpadded: global_load_lds layout
  __shared__ unsigned short Bs[128 * 32];
  const int nt = blockIdx.x;               // 0..47
  const int n0 = nt * 128;
  const int m0 = blockIdx.y * 128;
  const int t = threadIdx.x, w = t >> 6, lane = t & 63;
  const int wm = w >> 1, wn = w & 1;
  const int mcol = lane & 15, quad = lane >> 4;
  const int lrow = lane >> 2, lcol = (lane & 3) * 8;   // staging map (16B/lane)

  const unsigned short* Ag = Xb + (size_t)m0 * HID;
  const unsigned short* Bg = Wb + (size_t)n0 * HID;

  f32x4 acc[4][4];
  #pragma unroll
  for (int i = 0; i < 4; i++)
    #pragma unroll
    for (int j = 0; j < 4; j++) acc[i][j] = (f32x4){0.f, 0.f, 0.f, 0.f};

  for (int k0 = 0; k0 < HID; k0 += 32) {
    #pragma unroll
    for (int c2 = 0; c2 < 2; c2++) {
      const int c = w * 2 + c2;            // chunk: rows c*16..c*16+15
      gload_lds16(Ag + (size_t)(c*16 + lrow) * HID + k0 + lcol, &As[c * 512]);
      gload_lds16(Bg + (size_t)(c*16 + lrow) * HID + k0 + lcol, &Bs[c * 512]);
    }
    __syncthreads();                       // drains vmcnt -> LDS valid
    short8 af[4], bf[4];
    #pragma unroll
    for (int i = 0; i < 4; i++) af[i] = *(const short8*)&As[(wm*64 + i*16 + mcol)*32 + quad*8];
    #pragma unroll
    for (int j = 0; j < 4; j++) bf[j] = *(const short8*)&Bs[(wn*64 + j*16 + mcol)*32 + quad*8];
    #pragma unroll
    for (int i = 0; i < 4; i++)
      #pragma unroll
      for (int j = 0; j < 4; j++)
        acc[i][j] = __builtin_amdgcn_mfma_f32_16x16x32_bf16(af[i], bf[j], acc[i][j], 0, 0, 0);
    __syncthreads();
  }

  if (nt < 40) {
    unsigned short* dst = (nt < 32) ? (Qraw + (size_t)nt * HEAD_STRIDE)
                                    : (Kraw + (size_t)(nt - 32) * HEAD_STRIDE);
    #pragma unroll
    for (int i = 0; i < 4; i++) {
      const int rb = m0 + wm*64 + i*16 + quad*4;   // C/D: row=(lane>>4)*4+reg
      #pragma unroll
      for (int j = 0; j < 4; j++) {
        const int d = wn*64 + j*16 + mcol;         // col=lane&15
        #pragma unroll
        for (int r = 0; r < 4; r++)
          dst[(size_t)(rb + r) * HD + d] = f2bf(acc[i][j][r]);
      }
    }
  } else {
    unsigned short* dst = Vt + (size_t)(nt - 40) * HEAD_STRIDE;
    #pragma unroll
    for (int i = 0; i < 4; i++) {
      const int rb = m0 + wm*64 + i*16 + quad*4;   // 4 consecutive s per lane
      #pragma unroll
      for (int j = 0; j < 4; j++) {
        const int d = wn*64 + j*16 + mcol;
        ushort4 v4;
        v4.x = f2bf(acc[i][j][0]); v4.y = f2bf(acc[i][j][1]);
        v4.z = f2bf(acc[i][j][2]); v4.w = f2bf(acc[i][j][3]);
        *(ushort4*)(dst + (size_t)d * S_LEN + rb) = v4;
      }
    }
  }
}

// ---------------------------------------------------------------------------
// Kernel 2: RoPE in-place on bf16 Q and K. One wave per (head_row, s).
// ---------------------------------------------------------------------------
__global__ __launch_bounds__(256) void rope_qk_k(
    const int* __restrict__ pos_ids,
    unsigned short* __restrict__ Qraw, unsigned short* __restrict__ Kraw)
{
  const int w = threadIdx.x >> 6, lane = threadIdx.x & 63;
  const int gw = blockIdx.x * 4 + w;           // 0 .. (NH+NKV)*S-1
  const int hidx = gw >> 10;
  const int s = gw & 1023;
  const float pos = (float)pos_ids[s];
  const float invf = powf(10000.0f, -(float)lane * (1.0f / 64.0f));
  float sn, cs;
  sincosf(pos * invf, &sn, &cs);
  unsigned short* base = (hidx < NH)
      ? (Qraw + (size_t)hidx * HEAD_STRIDE + (size_t)s * HD)
      : (Kraw + (size_t)(hidx - NH) * HEAD_STRIDE + (size_t)s * HD);
  const float x0 = bf2f(base[lane]), x1 = bf2f(base[lane + 64]);
  base[lane]      = f2bf(x0 * cs - x1 * sn);
  base[lane + 64] = f2bf(x1 * cs + x0 * sn);
}

// ---------------------------------------------------------------------------
// Kernel 3: fused sparse attention, KT-specialized (KT = #128-key tiles).
//  Phase 1: per-kt scores -> double-buffered scb -> registers (1 barrier/kt).
//  Phase 2: bit-serial ballot radix-select, fully in registers/SGPR masks:
//    - M[c] = wave-uniform 64-bit candidate mask per 64-key chunk (SALU ops)
//    - per bit: 1 ballot per live chunk; dead chunks skipped (uniform branch)
//    - common sign/exponent prefix skipped via wave AND/OR of candidates
//    - early exit when #survivors == krem (all remaining candidates kept)
//    - no LDS histogram, no waitcnt fences, no shfl prefix scans
//    tie group at exit == final M[c]; tie ranks from popcll(M & lanemask_lt).
//  Phase 3: PV MFMA (P from LDS, V direct from global), epilogue scales.
// ---------------------------------------------------------------------------
#define PSTR 1040
template<int KT>
__device__ __forceinline__ void attn_body(
    const unsigned short* __restrict__ Qb, const unsigned short* __restrict__ Kh,
    const unsigned short* __restrict__ Vh, unsigned short* __restrict__ AO,
    unsigned short (*Pl)[PSTR], float* rowinv,
    int q0, int h, int w, int lane, int mcol, int quad)
{
  constexpr int NC = 2 * KT;                   // 64-key chunks per row
  const float scale = 0.08838834764831845f;    // 1/sqrt(128)
  float (*scb)[16][130] = (float (*)[16][130])&Pl[0][0];  // 2x8320 B overlay

  short8 aq[4];
  {
    const unsigned short* qrow = Qb + ((size_t)h * S_LEN + q0 + mcol) * HD + quad * 8;
    #pragma unroll
    for (int kk = 0; kk < 4; kk++) aq[kk] = *(const short8*)(qrow + kk * 32);
  }

  unsigned su[4][NC];                          // wave-owned rows w*4..w*4+3

  // ---- Phase 1: scores -> dbuf chunk transpose -> registers ----
  #pragma unroll
  for (int kt = 0; kt < KT; kt++) {
    short8 bfr[2][4];
    #pragma unroll
    for (int g2 = 0; g2 < 2; g2++) {
      const int key = kt * 128 + (w * 2 + g2) * 16 + mcol;
      const unsigned short* krow = Kh + (size_t)key * HD + quad * 8;
      #pragma unroll
      for (int kk = 0; kk < 4; kk++) bfr[g2][kk] = *(const short8*)(krow + kk * 32);
    }
    f32x4 d4[2];
    d4[0] = (f32x4){0.f,0.f,0.f,0.f}; d4[1] = (f32x4){0.f,0.f,0.f,0.f};
    #pragma unroll
    for (int g2 = 0; g2 < 2; g2++)
      #pragma unroll
      for (int kk = 0; kk < 4; kk++)
        d4[g2] = __builtin_amdgcn_mfma_f32_16x16x32_bf16(aq[kk], bfr[g2][kk], d4[g2], 0, 0, 0);
    #pragma unroll
    for (int g2 = 0; g2 < 2; g2++) {
      const int colc = (w * 2 + g2) * 16 + mcol;
      #pragma unroll
      for (int r = 0; r < 4; r++) scb[kt & 1][quad*4 + r][colc] = d4[g2][r] * scale;
    }
    __syncthreads();
    #pragma unroll
    for (int i = 0; i < 4; i++)
      #pragma unroll
      for (int sub = 0; sub < 2; sub++)
        su[i][kt*2 + sub] = ordf(scb[kt & 1][w*4 + i][sub*64 + lane]);
  }
  __syncthreads();                             // scb dead; Pl overlay safe

  // ---- Phase 2: ballot radix-select + softmax, all in registers ----
  const unsigned long long lmlt = (1ull << lane) - 1ull;
  #pragma unroll
  for (int i = 0; i < 4; i++) {
    const int r = w * 4 + i;
    const int q = q0 + r;
    const int L = q + 1;
    int ksel = L >> 1; if (ksel < 1) ksel = 1;

    // candidate masks per chunk (wave-uniform; computed scalar-side)
    unsigned long long M[NC];
    #pragma unroll
    for (int c = 0; c < NC; c++) {
      const int rem = L - c * 64;
      M[c] = rem >= 64 ? ~0ull : (rem <= 0 ? 0ull : ((1ull << rem) - 1ull));
    }

    // row max + common-prefix detection (wave reduces over candidates)
    unsigned um = 0, av = ~0u, ov = 0u;
    #pragma unroll
    for (int c = 0; c < NC; c++) {
      const int j = c * 64 + lane;
      if (j < L) {
        const unsigned u = su[i][c];
        if (u > um) um = u;
        av &= u; ov |= u;
      }
    }
    const float mx = iordf(wave_max_u(um));
    av = wave_and_u(av); ov = wave_or_u(ov);
    const unsigned diff = av ^ ov;
    const int hb = 31 - __builtin_clz(diff | 1u);      // highest informative bit
    const unsigned highmask = (hb >= 31) ? 0u : ~((1u << (hb + 1)) - 1u);

    int krem = ksel;
    int tot = L;
    unsigned tau = av & highmask, msk = highmask;
    #pragma unroll 1
    for (int b = hb; b >= 0; --b) {
      if (tot <= krem) break;                  // all survivors kept
      const unsigned bitm = 1u << b;
      int cnt = 0;
      #pragma unroll
      for (int c = 0; c < NC; c++)
        if (M[c]) cnt += (int)__popcll(__ballot(su[i][c] & bitm) & M[c]);
      const bool hi = cnt >= krem;
      msk |= bitm;
      if (hi) { tau |= bitm; tot = cnt; }
      else    { krem -= cnt; tot -= cnt; }
      #pragma unroll
      for (int c = 0; c < NC; c++)
        if (M[c]) {
          const unsigned long long B = __ballot(su[i][c] & bitm);
          M[c] &= hi ? B : ~B;
        }
    }
    // invariant: #{u&msk > tau} = ksel - krem; tie group == final M, budget krem

    // fused: keep + exp + unnormalized-P write + sum
    float ssum = 0.f;
    int cb = 0;                                // scalar rank base across chunks
    #pragma unroll
    for (int c = 0; c < NC; c++) {
      const int j = c * 64 + lane;
      const unsigned u = su[i][c];
      const unsigned umv = u & msk;
      const int trank = cb + (int)__popcll(M[c] & lmlt);
      cb += (int)__popcll(M[c]);
      const bool kept = (j < L) &&
          ((umv > tau) || (umv == tau && trank < krem) || (j < MIN_IDX));
      const float e = kept ? __expf(iordf(u) - mx) : 0.f;
      Pl[r][c*64 + lane] = f2bf(e);
      ssum += e;
    }
    ssum = wave_sum_f(ssum);
    if (lane == 0) rowinv[r] = 1.f / fmaxf(ssum, 1e-30f);
  }
  __syncthreads();

  // ---- Phase 3: PV (bf16 A from Pl, V direct from global) ----
  f32x4 opv[2];
  opv[0] = (f32x4){0.f,0.f,0.f,0.f}; opv[1] = (f32x4){0.f,0.f,0.f,0.f};
  #pragma unroll
  for (int kt = 0; kt < KT; kt++) {
    #pragma unroll
    for (int kb = 0; kb < 4; kb++) {
      short8 af = *(const short8*)&Pl[mcol][kt*128 + kb*32 + quad*8];
      #pragma unroll
      for (int n2 = 0; n2 < 2; n2++) {
        const int d = (w*2 + n2) * 16 + mcol;
        short8 bfr = *(const short8*)(Vh + (size_t)d * S_LEN + kt*128 + kb*32 + quad*8);
        opv[n2] = __builtin_amdgcn_mfma_f32_16x16x32_bf16(af, bfr, opv[n2], 0, 0, 0);
      }
    }
  }
  #pragma unroll
  for (int n2 = 0; n2 < 2; n2++) {
    const int col = h * HD + (w*2 + n2) * 16 + mcol;
    #pragma unroll
    for (int r2 = 0; r2 < 4; r2++) {
      const int row = q0 + quad*4 + r2;
      AO[(size_t)row * AO_COLS + col] = f2bf(opv[n2][r2] * rowinv[quad*4 + r2]);
    }
  }
}

__global__ __launch_bounds__(256, 4) void attn_k(
    const unsigned short* __restrict__ Qb, const unsigned short* __restrict__ Kb,
    const unsigned short* __restrict__ Vt, unsigned short* __restrict__ AO)
{
  __shared__ unsigned short Pl[16][PSTR];      // 33280 B
  __shared__ float rowinv[16];
  const int rb = (int)gridDim.x - 1 - (int)blockIdx.x;  // heavy blocks first
  const int h = blockIdx.y;
  const int kvh = h >> 2;                      // GROUPS=4
  const int q0 = rb * 16;
  const int kt_max = (rb >> 3) + 1;            // == (q0+16+127)>>7
  const int t = threadIdx.x, w = t >> 6, lane = t & 63;
  const int mcol = lane & 15, quad = lane >> 4;
  const unsigned short* Kh = Kb + (size_t)kvh * HEAD_STRIDE;  // [s][d]
  const unsigned short* Vh = Vt + (size_t)kvh * HEAD_STRIDE;  // [d][s]

  switch (kt_max) {
    case 1: attn_body<1>(Qb, Kh, Vh, AO, Pl, rowinv, q0, h, w, lane, mcol, quad); break;
    case 2: attn_body<2>(Qb, Kh, Vh, AO, Pl, rowinv, q0, h, w, lane, mcol, quad); break;
    case 3: attn_body<3>(Qb, Kh, Vh, AO, Pl, rowinv, q0, h, w, lane, mcol, quad); break;
    case 4: attn_body<4>(Qb, Kh, Vh, AO, Pl, rowinv, q0, h, w, lane, mcol, quad); break;
    case 5: attn_body<5>(Qb, Kh, Vh, AO, Pl, rowinv, q0, h, w, lane, mcol, quad); break;
    case 6: attn_body<6>(Qb, Kh, Vh, AO, Pl, rowinv, q0, h, w, lane, mcol, quad); break;
    case 7: attn_body<7>(Qb, Kh, Vh, AO, Pl, rowinv, q0, h, w, lane, mcol, quad); break;
    default: attn_body<8>(Qb, Kh, Vh, AO, Pl, rowinv, q0, h, w, lane, mcol, quad); break;
  }
}

// ---------------------------------------------------------------------------
// Kernel 4: output projection (all-bf16, m97-style global_load_lds).
// ---------------------------------------------------------------------------
__global__ __launch_bounds__(256) void gemm_out_k(
    const unsigned short* __restrict__ A, const unsigned short* __restrict__ Wob,
    float* __restrict__ Out)
{
  __shared__ unsigned short As[128 * 32];
  __shared__ unsigned short Bs[128 * 32];
  const int n0 = blockIdx.x * 128;
  const int m0 = blockIdx.y * 128;
  const int t = threadIdx.x, w = t >> 6, lane = t & 63;
  const int wm = w >> 1, wn = w & 1;
  const int mcol = lane & 15, quad = lane >> 4;
  const int lrow = lane >> 2, lcol = (lane & 3) * 8;

  const unsigned short* Ag = A   + (size_t)m0 * AO_COLS;
  const unsigned short* Bg = Wob + (size_t)n0 * AO_COLS;

  f32x4 acc[4][4];
  #pragma unroll
  for (int i = 0; i < 4; i++)
    #pragma unroll
    for (int j = 0; j < 4; j++) acc[i][j] = (f32x4){0.f, 0.f, 0.f, 0.f};

  for (int k0 = 0; k0 < AO_COLS; k0 += 32) {
    #pragma unroll
    for (int c2 = 0; c2 < 2; c2++) {
      const int c = w * 2 + c2;
      gload_lds16(Ag + (size_t)(c*16 + lrow) * AO_COLS + k0 + lcol, &As[c * 512]);
      gload_lds16(Bg + (size_t)(c*16 + lrow) * AO_COLS + k0 + lcol, &Bs[c * 512]);
    }
    __syncthreads();
    short8 af[4], bf[4];
    #pragma unroll
    for (int i = 0; i < 4; i++) af[i] = *(const short8*)&As[(wm*64 + i*16 + mcol)*32 + quad*8];
    #pragma unroll
    for (int j = 0; j < 4; j++) bf[j] = *(const short8*)&Bs[(wn*64 + j*16 + mcol)*32 + quad*8];
    #pragma unroll
    for (int i = 0; i < 4; i++)
      #pragma unroll
      for (int j = 0; j < 4; j++)
        acc[i][j] = __builtin_amdgcn_mfma_f32_16x16x32_bf16(af[i], bf[j], acc[i][j], 0, 0, 0);
    __syncthreads();
  }
  #pragma unroll
  for (int i = 0; i < 4; i++) {
    const int rb = m0 + wm*64 + i*16 + quad*4;
    #pragma unroll
    for (int j = 0; j < 4; j++) {
      const int col = n0 + wn*64 + j*16 + mcol;
      #pragma unroll
      for (int r = 0; r < 4; r++)
        Out[(size_t)(rb + r) * HID + col] = acc[i][j][r];
    }
  }
}

// ---------------------------------------------------------------------------
// Workspace layout (79,691,776 bytes total):
//   [0)          Qraw  bf16 [NH][S][HD]          8,388,608
//   [+8388608)   Kraw  bf16 [NKV][S][HD]         2,097,152
//   [+10485760)  Vt    bf16 [NKV][HD][S]         2,097,152
//   [+12582912)  AO    bf16 [S][NH*HD]           8,388,608
//   [+20971520)  Xb    bf16 [S][HID]             8,388,608
//   [+29360128)  Wqkvb bf16 [6144][4096]        50,331,648
//                Wob   bf16 [4096][4096] aliases Wqkvb (cvt after gemm_qkv)
// ---------------------------------------------------------------------------
extern "C" void kernel_launch(void* const* d_in, const int* in_sizes, int n_in,
                              void* d_out, int out_size, void* d_ws, size_t ws_size,
                              hipStream_t stream) {
  (void)in_sizes; (void)n_in; (void)out_size; (void)ws_size;
  const float* X   = (const float*)d_in[0];
  const int*   pos = (const int*)d_in[1];
  const float* Wq  = (const float*)d_in[2];
  const float* Wk  = (const float*)d_in[3];
  const float* Wv  = (const float*)d_in[4];
  const float* Wo  = (const float*)d_in[5];
  float* out = (float*)d_out;

  char* ws = (char*)d_ws;
  unsigned short* Qraw  = (unsigned short*)ws;
  unsigned short* Kraw  = (unsigned short*)(ws + 8388608);
  unsigned short* Vt    = (unsigned short*)(ws + 10485760);
  unsigned short* AO    = (unsigned short*)(ws + 12582912);
  unsigned short* Xb    = (unsigned short*)(ws + 20971520);
  unsigned short* Wqkvb = (unsigned short*)(ws + 29360128);
  unsigned short* Wob   = Wqkvb;   // alias: Wo converted after gemm_qkv reads Wqkvb

  // bf16 conversions (memory-bound; 8 elems/thread)
  cvt_k<<<dim3(2048), dim3(256), 0, stream>>>(X,  Xb);                       // 4.19M
  cvt_k<<<dim3(8192), dim3(256), 0, stream>>>(Wq, Wqkvb);                    // 16.8M
  cvt_k<<<dim3(2048), dim3(256), 0, stream>>>(Wk, Wqkvb + 16777216);         // 4.19M
  cvt_k<<<dim3(2048), dim3(256), 0, stream>>>(Wv, Wqkvb + 20971520);         // 4.19M

  gemm_qkv_k<<<dim3(48, 8),  dim3(256), 0, stream>>>(Xb, Wqkvb, Qraw, Kraw, Vt);
  rope_qk_k <<<dim3(10240),  dim3(256), 0, stream>>>(pos, Qraw, Kraw);

  cvt_k<<<dim3(8192), dim3(256), 0, stream>>>(Wo, Wob);                      // 16.8M

  attn_k    <<<dim3(64, 32), dim3(256), 0, stream>>>(Qraw, Kraw, Vt, AO);
  gemm_out_k<<<dim3(32, 8),  dim3(256), 0, stream>>>(AO, Wob, out);
}

// Round 2
// 537.181 us; speedup vs baseline: 1.1234x; 1.1234x over previous
//
#include <hip/hip_runtime.h>
#include <hip/hip_bf16.h>

// Problem constants
#define S_LEN 1024
#define HID   4096
#define NH    32
#define NKV   8
#define HD    128
#define MIN_IDX 4
#define AO_COLS 4096        // NH*HD
#define HEAD_STRIDE 131072  // S_LEN*HD

typedef __attribute__((ext_vector_type(8))) short short8;
typedef __attribute__((ext_vector_type(4))) float f32x4;

__device__ __forceinline__ unsigned short f2bf(float f) {
  union { float f; unsigned u; } v; v.f = f;
  unsigned r = v.u + 0x7FFFu + ((v.u >> 16) & 1u);   // RNE
  return (unsigned short)(r >> 16);
}
__device__ __forceinline__ float bf2f(unsigned short h) {
  union { unsigned u; float f; } v; v.u = ((unsigned)h) << 16;
  return v.f;
}
__device__ __forceinline__ unsigned pk2(float a, float b) {
  union { __hip_bfloat162 h; unsigned u; } c;
  c.h = __float22bfloat162_rn(make_float2(a, b));    // v_cvt_pk_bf16_f32
  return c.u;
}
__device__ __forceinline__ short8 pack8(float4 a, float4 b) {
  union { short8 s; unsigned u[4]; } r;
  r.u[0] = pk2(a.x, a.y); r.u[1] = pk2(a.z, a.w);
  r.u[2] = pk2(b.x, b.y); r.u[3] = pk2(b.z, b.w);
  return r.s;
}
// float -> order-preserving uint, and inverse
__device__ __forceinline__ unsigned ordf(float f) {
  union { float f; int i; } v; v.f = f;
  return (unsigned)(v.i ^ ((v.i >> 31) | 0x80000000));
}
__device__ __forceinline__ float iordf(unsigned u) {
  union { int i; float f; } v;
  v.i = (u & 0x80000000u) ? (int)(u ^ 0x80000000u) : (int)~u;
  return v.f;
}
__device__ __forceinline__ float wave_sum_f(float v) {
  #pragma unroll
  for (int m = 32; m >= 1; m >>= 1) v += __shfl_xor(v, m);
  return v;
}
__device__ __forceinline__ unsigned wave_max_u(unsigned v) {
  #pragma unroll
  for (int m = 32; m >= 1; m >>= 1) { unsigned o = __shfl_xor(v, m); v = o > v ? o : v; }
  return v;
}
// wave-local LDS fence: hist[w] is wave-private, so no block barrier needed.
// Wait lgkmcnt(0) only (vmcnt=63, expcnt=7 -> don't wait): imm = 0xC07F.
__device__ __forceinline__ void wave_lds_fence() {
  __builtin_amdgcn_s_waitcnt(0xC07F);
  __builtin_amdgcn_wave_barrier();      // stop compiler reordering
}
// async global->LDS, 16 B per lane. LDS dest: wave-uniform base + lane*16.
__device__ __forceinline__ void gload_lds16(const unsigned short* g, unsigned short* l) {
  auto gp = (const __attribute__((address_space(1))) unsigned*)g;
  auto lp = (__attribute__((address_space(3))) unsigned*)(unsigned)(unsigned long long)l;
  __builtin_amdgcn_global_load_lds(gp, lp, 16, 0, 0);
}

// ---------------------------------------------------------------------------
// Kernel 0: fp32 -> bf16 convert (8 elems/thread). n must be multiple of 2048.
// ---------------------------------------------------------------------------
__global__ __launch_bounds__(256) void cvt_k(
    const float* __restrict__ src, unsigned short* __restrict__ dst)
{
  const size_t i = ((size_t)blockIdx.x * 256 + threadIdx.x) * 8;
  float4 a = *(const float4*)(src + i);
  float4 b = *(const float4*)(src + i + 4);
  *(short8*)(dst + i) = pack8(a, b);
}

// ---------------------------------------------------------------------------
// Kernel 1: QKV projection (NT gemm, all-bf16, m97-style global_load_lds).
// ---------------------------------------------------------------------------
__global__ __launch_bounds__(256) void gemm_qkv_k(
    const unsigned short* __restrict__ Xb, const unsigned short* __restrict__ Wb,
    unsigned short* __restrict__ Qraw, unsigned short* __restrict__ Kraw,
    unsigned short* __restrict__ Vt)
{
  __shared__ unsigned short As[128 * 32];  // unpadded: global_load_lds layout
  __shared__ unsigned short Bs[128 * 32];
  const int nt = blockIdx.x;               // 0..47
  const int n0 = nt * 128;
  const int m0 = blockIdx.y * 128;
  const int t = threadIdx.x, w = t >> 6, lane = t & 63;
  const int wm = w >> 1, wn = w & 1;
  const int mcol = lane & 15, quad = lane >> 4;
  const int lrow = lane >> 2, lcol = (lane & 3) * 8;   // staging map (16B/lane)

  const unsigned short* Ag = Xb + (size_t)m0 * HID;
  const unsigned short* Bg = Wb + (size_t)n0 * HID;

  f32x4 acc[4][4];
  #pragma unroll
  for (int i = 0; i < 4; i++)
    #pragma unroll
    for (int j = 0; j < 4; j++) acc[i][j] = (f32x4){0.f, 0.f, 0.f, 0.f};

  for (int k0 = 0; k0 < HID; k0 += 32) {
    #pragma unroll
    for (int c2 = 0; c2 < 2; c2++) {
      const int c = w * 2 + c2;            // chunk: rows c*16..c*16+15
      gload_lds16(Ag + (size_t)(c*16 + lrow) * HID + k0 + lcol, &As[c * 512]);
      gload_lds16(Bg + (size_t)(c*16 + lrow) * HID + k0 + lcol, &Bs[c * 512]);
    }
    __syncthreads();                       // drains vmcnt -> LDS valid
    short8 af[4], bf[4];
    #pragma unroll
    for (int i = 0; i < 4; i++) af[i] = *(const short8*)&As[(wm*64 + i*16 + mcol)*32 + quad*8];
    #pragma unroll
    for (int j = 0; j < 4; j++) bf[j] = *(const short8*)&Bs[(wn*64 + j*16 + mcol)*32 + quad*8];
    #pragma unroll
    for (int i = 0; i < 4; i++)
      #pragma unroll
      for (int j = 0; j < 4; j++)
        acc[i][j] = __builtin_amdgcn_mfma_f32_16x16x32_bf16(af[i], bf[j], acc[i][j], 0, 0, 0);
    __syncthreads();
  }

  if (nt < 40) {
    unsigned short* dst = (nt < 32) ? (Qraw + (size_t)nt * HEAD_STRIDE)
                                    : (Kraw + (size_t)(nt - 32) * HEAD_STRIDE);
    #pragma unroll
    for (int i = 0; i < 4; i++) {
      const int rb = m0 + wm*64 + i*16 + quad*4;   // C/D: row=(lane>>4)*4+reg
      #pragma unroll
      for (int j = 0; j < 4; j++) {
        const int d = wn*64 + j*16 + mcol;         // col=lane&15
        #pragma unroll
        for (int r = 0; r < 4; r++)
          dst[(size_t)(rb + r) * HD + d] = f2bf(acc[i][j][r]);
      }
    }
  } else {
    unsigned short* dst = Vt + (size_t)(nt - 40) * HEAD_STRIDE;
    #pragma unroll
    for (int i = 0; i < 4; i++) {
      const int rb = m0 + wm*64 + i*16 + quad*4;   // 4 consecutive s per lane
      #pragma unroll
      for (int j = 0; j < 4; j++) {
        const int d = wn*64 + j*16 + mcol;
        ushort4 v4;
        v4.x = f2bf(acc[i][j][0]); v4.y = f2bf(acc[i][j][1]);
        v4.z = f2bf(acc[i][j][2]); v4.w = f2bf(acc[i][j][3]);
        *(ushort4*)(dst + (size_t)d * S_LEN + rb) = v4;
      }
    }
  }
}

// ---------------------------------------------------------------------------
// Kernel 2: RoPE in-place on bf16 Q and K. One wave per (head_row, s).
// ---------------------------------------------------------------------------
__global__ __launch_bounds__(256) void rope_qk_k(
    const int* __restrict__ pos_ids,
    unsigned short* __restrict__ Qraw, unsigned short* __restrict__ Kraw)
{
  const int w = threadIdx.x >> 6, lane = threadIdx.x & 63;
  const int gw = blockIdx.x * 4 + w;           // 0 .. (NH+NKV)*S-1
  const int hidx = gw >> 10;
  const int s = gw & 1023;
  const float pos = (float)pos_ids[s];
  const float invf = powf(10000.0f, -(float)lane * (1.0f / 64.0f));
  float sn, cs;
  sincosf(pos * invf, &sn, &cs);
  unsigned short* base = (hidx < NH)
      ? (Qraw + (size_t)hidx * HEAD_STRIDE + (size_t)s * HD)
      : (Kraw + (size_t)(hidx - NH) * HEAD_STRIDE + (size_t)s * HD);
  const float x0 = bf2f(base[lane]), x1 = bf2f(base[lane + 64]);
  base[lane]      = f2bf(x0 * cs - x1 * sn);
  base[lane + 64] = f2bf(x1 * cs + x0 * sn);
}

// ---------------------------------------------------------------------------
// Kernel 3: fused sparse attention, KT-specialized (KT = #128-key tiles).
//  Phase 1: per-kt scores -> double-buffered scb -> registers (1 barrier/kt).
//  Phase 2: radix-select, fence-minimized:
//    - 2 histogram passes (bits 31:24, 23:16), rows PACKED pairwise into
//      16-bit fields of one 256-word histogram -> 2 fence pairs per pass
//      (8 total per wave vs 32 in the 4-pass/row-serial version), one packed
//      shfl_up scan serves 2 rows (counts <= 1024, no field carry).
//    - residual bits 15:0 resolved by STATELESS ballot refinement
//      (membership recomputed from (su & bmsk) == btau; no mask arrays,
//      no spills); invariant tot >= krem => loop usually runs 0 iters.
//    - exact top-k, index-stable ties (same kept-set as full 32-bit select).
//  Phase 3: PV MFMA (P from LDS, V direct from global), epilogue scales.
// ---------------------------------------------------------------------------
#define PSTR 1040
template<int KT>
__device__ __forceinline__ void attn_body(
    const unsigned short* __restrict__ Qb, const unsigned short* __restrict__ Kh,
    const unsigned short* __restrict__ Vh, unsigned short* __restrict__ AO,
    unsigned short (*Pl)[PSTR], unsigned (*hist)[256], float* rowinv,
    int q0, int h, int w, int lane, int mcol, int quad)
{
  constexpr int NC = 2 * KT;                   // 64-key chunks per row
  const float scale = 0.08838834764831845f;    // 1/sqrt(128)
  float (*scb)[16][130] = (float (*)[16][130])&Pl[0][0];  // 2x8320 B overlay

  short8 aq[4];
  {
    const unsigned short* qrow = Qb + ((size_t)h * S_LEN + q0 + mcol) * HD + quad * 8;
    #pragma unroll
    for (int kk = 0; kk < 4; kk++) aq[kk] = *(const short8*)(qrow + kk * 32);
  }

  unsigned su[4][NC];                          // wave-owned rows w*4..w*4+3

  // ---- Phase 1: scores -> dbuf chunk transpose -> registers ----
  #pragma unroll
  for (int kt = 0; kt < KT; kt++) {
    short8 bfr[2][4];
    #pragma unroll
    for (int g2 = 0; g2 < 2; g2++) {
      const int key = kt * 128 + (w * 2 + g2) * 16 + mcol;
      const unsigned short* krow = Kh + (size_t)key * HD + quad * 8;
      #pragma unroll
      for (int kk = 0; kk < 4; kk++) bfr[g2][kk] = *(const short8*)(krow + kk * 32);
    }
    f32x4 d4[2];
    d4[0] = (f32x4){0.f,0.f,0.f,0.f}; d4[1] = (f32x4){0.f,0.f,0.f,0.f};
    #pragma unroll
    for (int g2 = 0; g2 < 2; g2++)
      #pragma unroll
      for (int kk = 0; kk < 4; kk++)
        d4[g2] = __builtin_amdgcn_mfma_f32_16x16x32_bf16(aq[kk], bfr[g2][kk], d4[g2], 0, 0, 0);
    #pragma unroll
    for (int g2 = 0; g2 < 2; g2++) {
      const int colc = (w * 2 + g2) * 16 + mcol;
      #pragma unroll
      for (int r = 0; r < 4; r++) scb[kt & 1][quad*4 + r][colc] = d4[g2][r] * scale;
    }
    __syncthreads();
    #pragma unroll
    for (int i = 0; i < 4; i++)
      #pragma unroll
      for (int sub = 0; sub < 2; sub++)
        su[i][kt*2 + sub] = ordf(scb[kt & 1][w*4 + i][sub*64 + lane]);
  }
  __syncthreads();                             // scb dead; Pl overlay safe

  // ---- Phase 2: fence-minimized radix select + softmax ----
  const unsigned long long lmlt = (1ull << lane) - 1ull;
  int Lr[4], krem[4], tot[4];
  unsigned prefix[4];
  #pragma unroll
  for (int i = 0; i < 4; i++) {
    Lr[i] = q0 + w*4 + i + 1;
    int ks = Lr[i] >> 1; if (ks < 1) ks = 1;
    krem[i] = ks; tot[i] = Lr[i]; prefix[i] = 0u;
  }

  unsigned msk = 0u;
  #pragma unroll
  for (int pass = 0; pass < 2; pass++) {
    const int shift = 24 - pass * 8;
    #pragma unroll
    for (int p = 0; p < 2; p++) {              // row pair: rows p*2, p*2+1
      { uint4 z = {0u, 0u, 0u, 0u}; *(uint4*)&hist[w][lane * 4] = z; }
      wave_lds_fence();
      #pragma unroll
      for (int c = 0; c < NC; c++) {
        const int j = c * 64 + lane;
        #pragma unroll
        for (int rr = 0; rr < 2; rr++) {
          const int i = p * 2 + rr;
          if (j < Lr[i] && (su[i][c] & msk) == prefix[i])
            atomicAdd(&hist[w][(su[i][c] >> shift) & 255], 1u << (16 * rr));
        }
      }
      wave_lds_fence();
      // packed descending scan (one scan serves both rows of the pair)
      const uint4 cv = *(const uint4*)&hist[w][252 - lane * 4];
      unsigned c4[4] = { cv.w, cv.z, cv.y, cv.x };   // descending bins
      const unsigned lsum = c4[0] + c4[1] + c4[2] + c4[3];
      unsigned x = lsum;
      #pragma unroll
      for (int d2 = 1; d2 < 64; d2 <<= 1) { unsigned y = __shfl_up(x, d2); if (lane >= d2) x += y; }
      const unsigned runp = x - lsum;
      #pragma unroll
      for (int rr = 0; rr < 2; rr++) {
        const int i = p * 2 + rr;
        const int sh16 = 16 * rr;
        int run = (int)((runp >> sh16) & 0xFFFFu);
        int fbin = -1, fbefore = 0, fcnt = 0;
        #pragma unroll
        for (int j2 = 0; j2 < 4; j2++) {
          const int cnum = (int)((c4[j2] >> sh16) & 0xFFFFu);
          if (fbin < 0 && run < krem[i] && run + cnum >= krem[i]) {
            fbin = 255 - lane*4 - j2; fbefore = run; fcnt = cnum;
          }
          run += cnum;
        }
        const unsigned long long bal = __ballot(fbin >= 0);
        int bin = 0, before = 0, cnt = krem[i];
        if (bal != 0ull) {
          const int srcl = __ffsll((unsigned long long)bal) - 1;
          bin = __shfl(fbin, srcl);
          before = __shfl(fbefore, srcl);
          cnt = __shfl(fcnt, srcl);
          if (bin < 0) bin = 0;
        }
        krem[i] -= before; if (krem[i] < 1) krem[i] = 1;
        tot[i] = cnt;
        prefix[i] |= ((unsigned)bin) << shift;
      }
    }
    msk |= 0xFFu << (24 - pass * 8);
  }

  // ---- per-row residual refinement + fused exp/write sweep ----
  #pragma unroll
  for (int i = 0; i < 4; i++) {
    const int r = w * 4 + i;
    const int L = Lr[i];
    unsigned btau = prefix[i];
    unsigned bmsk = 0xFFFF0000u;
    int kr = krem[i];
    int tt = tot[i];
    // stateless bit-serial refinement of bits 15:0 (usually 0 iterations:
    // invariant tt >= kr, and after 16 bits the tie group is tiny)
    #pragma unroll 1
    for (int b = 15; b >= 0; --b) {
      if (tt <= kr) break;
      const unsigned bit = 1u << b;
      const unsigned am = bmsk | bit;
      const unsigned test = btau | bit;
      int cnt = 0;
      #pragma unroll
      for (int c = 0; c < NC; c++) {
        const int j = c * 64 + lane;
        cnt += (int)__popcll(__ballot(j < L && (su[i][c] & am) == test));
      }
      if (cnt >= kr) { btau = test; tt = cnt; }
      else           { kr -= cnt; tt -= cnt; }
      bmsk = am;
    }

    // mx = max over kept = row max (rank-1 element always kept)
    unsigned um = 0;
    #pragma unroll
    for (int c = 0; c < NC; c++) {
      const int j = c * 64 + lane;
      if (j < L && su[i][c] > um) um = su[i][c];
    }
    const float mx = iordf(wave_max_u(um));

    // fused: keep + exp + unnormalized-P write + sum
    float ssum = 0.f;
    int tiebase = 0;
    #pragma unroll
    for (int c = 0; c < NC; c++) {
      const int j = c * 64 + lane;
      const unsigned u = su[i][c];
      const unsigned umv = u & bmsk;
      const bool eq = (j < L) && (umv == btau);
      const unsigned long long bal = __ballot(eq);
      const int trank = tiebase + (int)__popcll(bal & lmlt);
      tiebase += (int)__popcll(bal);
      const bool kept = (j < L) &&
          ((umv > btau) || (eq && trank < kr) || (j < MIN_IDX));
      const float e = kept ? __expf(iordf(u) - mx) : 0.f;
      Pl[r][c*64 + lane] = f2bf(e);
      ssum += e;
    }
    ssum = wave_sum_f(ssum);
    if (lane == 0) rowinv[r] = 1.f / fmaxf(ssum, 1e-30f);
  }
  __syncthreads();

  // ---- Phase 3: PV (bf16 A from Pl, V direct from global) ----
  f32x4 opv[2];
  opv[0] = (f32x4){0.f,0.f,0.f,0.f}; opv[1] = (f32x4){0.f,0.f,0.f,0.f};
  #pragma unroll
  for (int kt = 0; kt < KT; kt++) {
    #pragma unroll
    for (int kb = 0; kb < 4; kb++) {
      short8 af = *(const short8*)&Pl[mcol][kt*128 + kb*32 + quad*8];
      #pragma unroll
      for (int n2 = 0; n2 < 2; n2++) {
        const int d = (w*2 + n2) * 16 + mcol;
        short8 bfr = *(const short8*)(Vh + (size_t)d * S_LEN + kt*128 + kb*32 + quad*8);
        opv[n2] = __builtin_amdgcn_mfma_f32_16x16x32_bf16(af, bfr, opv[n2], 0, 0, 0);
      }
    }
  }
  #pragma unroll
  for (int n2 = 0; n2 < 2; n2++) {
    const int col = h * HD + (w*2 + n2) * 16 + mcol;
    #pragma unroll
    for (int r2 = 0; r2 < 4; r2++) {
      const int row = q0 + quad*4 + r2;
      AO[(size_t)row * AO_COLS + col] = f2bf(opv[n2][r2] * rowinv[quad*4 + r2]);
    }
  }
}

__global__ __launch_bounds__(256, 4) void attn_k(
    const unsigned short* __restrict__ Qb, const unsigned short* __restrict__ Kb,
    const unsigned short* __restrict__ Vt, unsigned short* __restrict__ AO)
{
  __shared__ unsigned short Pl[16][PSTR];      // 33280 B
  __shared__ unsigned hist[4][256];            // 4096 B (wave-private rows)
  __shared__ float rowinv[16];
  const int rb = (int)gridDim.x - 1 - (int)blockIdx.x;  // heavy blocks first
  const int h = blockIdx.y;
  const int kvh = h >> 2;                      // GROUPS=4
  const int q0 = rb * 16;
  const int kt_max = (rb >> 3) + 1;            // == (q0+16+127)>>7
  const int t = threadIdx.x, w = t >> 6, lane = t & 63;
  const int mcol = lane & 15, quad = lane >> 4;
  const unsigned short* Kh = Kb + (size_t)kvh * HEAD_STRIDE;  // [s][d]
  const unsigned short* Vh = Vt + (size_t)kvh * HEAD_STRIDE;  // [d][s]

  switch (kt_max) {
    case 1: attn_body<1>(Qb, Kh, Vh, AO, Pl, hist, rowinv, q0, h, w, lane, mcol, quad); break;
    case 2: attn_body<2>(Qb, Kh, Vh, AO, Pl, hist, rowinv, q0, h, w, lane, mcol, quad); break;
    case 3: attn_body<3>(Qb, Kh, Vh, AO, Pl, hist, rowinv, q0, h, w, lane, mcol, quad); break;
    case 4: attn_body<4>(Qb, Kh, Vh, AO, Pl, hist, rowinv, q0, h, w, lane, mcol, quad); break;
    case 5: attn_body<5>(Qb, Kh, Vh, AO, Pl, hist, rowinv, q0, h, w, lane, mcol, quad); break;
    case 6: attn_body<6>(Qb, Kh, Vh, AO, Pl, hist, rowinv, q0, h, w, lane, mcol, quad); break;
    case 7: attn_body<7>(Qb, Kh, Vh, AO, Pl, hist, rowinv, q0, h, w, lane, mcol, quad); break;
    default: attn_body<8>(Qb, Kh, Vh, AO, Pl, hist, rowinv, q0, h, w, lane, mcol, quad); break;
  }
}

// ---------------------------------------------------------------------------
// Kernel 4: output projection (all-bf16, m97-style global_load_lds).
// ---------------------------------------------------------------------------
__global__ __launch_bounds__(256) void gemm_out_k(
    const unsigned short* __restrict__ A, const unsigned short* __restrict__ Wob,
    float* __restrict__ Out)
{
  __shared__ unsigned short As[128 * 32];
  __shared__ unsigned short Bs[128 * 32];
  const int n0 = blockIdx.x * 128;
  const int m0 = blockIdx.y * 128;
  const int t = threadIdx.x, w = t >> 6, lane = t & 63;
  const int wm = w >> 1, wn = w & 1;
  const int mcol = lane & 15, quad = lane >> 4;
  const int lrow = lane >> 2, lcol = (lane & 3) * 8;

  const unsigned short* Ag = A   + (size_t)m0 * AO_COLS;
  const unsigned short* Bg = Wob + (size_t)n0 * AO_COLS;

  f32x4 acc[4][4];
  #pragma unroll
  for (int i = 0; i < 4; i++)
    #pragma unroll
    for (int j = 0; j < 4; j++) acc[i][j] = (f32x4){0.f, 0.f, 0.f, 0.f};

  for (int k0 = 0; k0 < AO_COLS; k0 += 32) {
    #pragma unroll
    for (int c2 = 0; c2 < 2; c2++) {
      const int c = w * 2 + c2;
      gload_lds16(Ag + (size_t)(c*16 + lrow) * AO_COLS + k0 + lcol, &As[c * 512]);
      gload_lds16(Bg + (size_t)(c*16 + lrow) * AO_COLS + k0 + lcol, &Bs[c * 512]);
    }
    __syncthreads();
    short8 af[4], bf[4];
    #pragma unroll
    for (int i = 0; i < 4; i++) af[i] = *(const short8*)&As[(wm*64 + i*16 + mcol)*32 + quad*8];
    #pragma unroll
    for (int j = 0; j < 4; j++) bf[j] = *(const short8*)&Bs[(wn*64 + j*16 + mcol)*32 + quad*8];
    #pragma unroll
    for (int i = 0; i < 4; i++)
      #pragma unroll
      for (int j = 0; j < 4; j++)
        acc[i][j] = __builtin_amdgcn_mfma_f32_16x16x32_bf16(af[i], bf[j], acc[i][j], 0, 0, 0);
    __syncthreads();
  }
  #pragma unroll
  for (int i = 0; i < 4; i++) {
    const int rb = m0 + wm*64 + i*16 + quad*4;
    #pragma unroll
    for (int j = 0; j < 4; j++) {
      const int col = n0 + wn*64 + j*16 + mcol;
      #pragma unroll
      for (int r = 0; r < 4; r++)
        Out[(size_t)(rb + r) * HID + col] = acc[i][j][r];
    }
  }
}

// ---------------------------------------------------------------------------
// Workspace layout (79,691,776 bytes total):
//   [0)          Qraw  bf16 [NH][S][HD]          8,388,608
//   [+8388608)   Kraw  bf16 [NKV][S][HD]         2,097,152
//   [+10485760)  Vt    bf16 [NKV][HD][S]         2,097,152
//   [+12582912)  AO    bf16 [S][NH*HD]           8,388,608
//   [+20971520)  Xb    bf16 [S][HID]             8,388,608
//   [+29360128)  Wqkvb bf16 [6144][4096]        50,331,648
//                Wob   bf16 [4096][4096] aliases Wqkvb (cvt after gemm_qkv)
// ---------------------------------------------------------------------------
extern "C" void kernel_launch(void* const* d_in, const int* in_sizes, int n_in,
                              void* d_out, int out_size, void* d_ws, size_t ws_size,
                              hipStream_t stream) {
  (void)in_sizes; (void)n_in; (void)out_size; (void)ws_size;
  const float* X   = (const float*)d_in[0];
  const int*   pos = (const int*)d_in[1];
  const float* Wq  = (const float*)d_in[2];
  const float* Wk  = (const float*)d_in[3];
  const float* Wv  = (const float*)d_in[4];
  const float* Wo  = (const float*)d_in[5];
  float* out = (float*)d_out;

  char* ws = (char*)d_ws;
  unsigned short* Qraw  = (unsigned short*)ws;
  unsigned short* Kraw  = (unsigned short*)(ws + 8388608);
  unsigned short* Vt    = (unsigned short*)(ws + 10485760);
  unsigned short* AO    = (unsigned short*)(ws + 12582912);
  unsigned short* Xb    = (unsigned short*)(ws + 20971520);
  unsigned short* Wqkvb = (unsigned short*)(ws + 29360128);
  unsigned short* Wob   = Wqkvb;   // alias: Wo converted after gemm_qkv reads Wqkvb

  // bf16 conversions (memory-bound; 8 elems/thread)
  cvt_k<<<dim3(2048), dim3(256), 0, stream>>>(X,  Xb);                       // 4.19M
  cvt_k<<<dim3(8192), dim3(256), 0, stream>>>(Wq, Wqkvb);                    // 16.8M
  cvt_k<<<dim3(2048), dim3(256), 0, stream>>>(Wk, Wqkvb + 16777216);         // 4.19M
  cvt_k<<<dim3(2048), dim3(256), 0, stream>>>(Wv, Wqkvb + 20971520);         // 4.19M

  gemm_qkv_k<<<dim3(48, 8),  dim3(256), 0, stream>>>(Xb, Wqkvb, Qraw, Kraw, Vt);
  rope_qk_k <<<dim3(10240),  dim3(256), 0, stream>>>(pos, Qraw, Kraw);

  cvt_k<<<dim3(8192), dim3(256), 0, stream>>>(Wo, Wob);                      // 16.8M

  attn_k    <<<dim3(64, 32), dim3(256), 0, stream>>>(Qraw, Kraw, Vt, AO);
  gemm_out_k<<<dim3(32, 8),  dim3(256), 0, stream>>>(AO, Wob, out);
}

// Round 6
// 456.377 us; speedup vs baseline: 1.3222x; 1.1771x over previous
//
#include <hip/hip_runtime.h>
#include <hip/hip_bf16.h>

// Problem constants
#define S_LEN 1024
#define HID   4096
#define NH    32
#define NKV   8
#define HD    128
#define MIN_IDX 4
#define AO_COLS 4096        // NH*HD
#define HEAD_STRIDE 131072  // S_LEN*HD

typedef __attribute__((ext_vector_type(8))) short short8;
typedef __attribute__((ext_vector_type(4))) float f32x4;

__device__ __forceinline__ unsigned short f2bf(float f) {
  union { float f; unsigned u; } v; v.f = f;
  unsigned r = v.u + 0x7FFFu + ((v.u >> 16) & 1u);   // RNE
  return (unsigned short)(r >> 16);
}
__device__ __forceinline__ float bf2f(unsigned short h) {
  union { unsigned u; float f; } v; v.u = ((unsigned)h) << 16;
  return v.f;
}
__device__ __forceinline__ unsigned pk2(float a, float b) {
  union { __hip_bfloat162 h; unsigned u; } c;
  c.h = __float22bfloat162_rn(make_float2(a, b));    // v_cvt_pk_bf16_f32
  return c.u;
}
__device__ __forceinline__ short8 pack8(float4 a, float4 b) {
  union { short8 s; unsigned u[4]; } r;
  r.u[0] = pk2(a.x, a.y); r.u[1] = pk2(a.z, a.w);
  r.u[2] = pk2(b.x, b.y); r.u[3] = pk2(b.z, b.w);
  return r.s;
}
// float -> order-preserving uint, and inverse
__device__ __forceinline__ unsigned ordf(float f) {
  union { float f; int i; } v; v.f = f;
  return (unsigned)(v.i ^ ((v.i >> 31) | 0x80000000));
}
__device__ __forceinline__ float iordf(unsigned u) {
  union { int i; float f; } v;
  v.i = (u & 0x80000000u) ? (int)(u ^ 0x80000000u) : (int)~u;
  return v.f;
}
__device__ __forceinline__ float wave_sum_f(float v) {
  #pragma unroll
  for (int m = 32; m >= 1; m >>= 1) v += __shfl_xor(v, m);
  return v;
}
__device__ __forceinline__ unsigned wave_max_u(unsigned v) {
  #pragma unroll
  for (int m = 32; m >= 1; m >>= 1) { unsigned o = __shfl_xor(v, m); v = o > v ? o : v; }
  return v;
}
// wave-local LDS fence: hist[w] is wave-private, so no block barrier needed.
// Wait lgkmcnt(0) only (vmcnt=63, expcnt=7 -> don't wait): imm = 0xC07F.
__device__ __forceinline__ void wave_lds_fence() {
  __builtin_amdgcn_s_waitcnt(0xC07F);
  __builtin_amdgcn_wave_barrier();      // stop compiler reordering
}
// async global->LDS, 16 B per lane. LDS dest: wave-uniform base + lane*16.
__device__ __forceinline__ void gload_lds16(const unsigned short* g, unsigned short* l) {
  auto gp = (const __attribute__((address_space(1))) unsigned*)g;
  auto lp = (__attribute__((address_space(3))) unsigned*)(unsigned)(unsigned long long)l;
  __builtin_amdgcn_global_load_lds(gp, lp, 16, 0, 0);
}

// ---------------------------------------------------------------------------
// Kernel 0: fp32 -> bf16 convert (8 elems/thread). n must be multiple of 2048.
// ---------------------------------------------------------------------------
__global__ __launch_bounds__(256) void cvt_k(
    const float* __restrict__ src, unsigned short* __restrict__ dst)
{
  const size_t i = ((size_t)blockIdx.x * 256 + threadIdx.x) * 8;
  float4 a = *(const float4*)(src + i);
  float4 b = *(const float4*)(src + i + 4);
  *(short8*)(dst + i) = pack8(a, b);
}

// Fused convert of X, Wq, Wk, Wv in one launch (14336 blocks, 2048 elem/blk).
__global__ __launch_bounds__(256) void cvt4_k(
    const float* __restrict__ s0, const float* __restrict__ s1,
    const float* __restrict__ s2, const float* __restrict__ s3,
    unsigned short* __restrict__ d0, unsigned short* __restrict__ d1)
{
  const int b = blockIdx.x;
  const float* src; unsigned short* dst; int rb;
  if (b < 2048)       { src = s0; dst = d0;            rb = b; }
  else if (b < 10240) { src = s1; dst = d1;            rb = b - 2048; }
  else if (b < 12288) { src = s2; dst = d1 + 16777216; rb = b - 10240; }
  else                { src = s3; dst = d1 + 20971520; rb = b - 12288; }
  const size_t i = ((size_t)rb * 256 + threadIdx.x) * 8;
  float4 a = *(const float4*)(src + i);
  float4 c = *(const float4*)(src + i + 4);
  *(short8*)(dst + i) = pack8(a, c);
}

// ---------------------------------------------------------------------------
// Kernel 1: QKV projection (NT gemm, all-bf16).
// Depth-2 software pipeline: triple-buffered LDS, raw s_barrier + counted
// s_waitcnt vmcnt(4) (never full drain in steady state). Tile t+2 staged
// while tile t computes -> global latency hidden under MFMA.
// ---------------------------------------------------------------------------
__global__ __launch_bounds__(256) void gemm_qkv_k(
    const unsigned short* __restrict__ Xb, const unsigned short* __restrict__ Wb,
    unsigned short* __restrict__ Qraw, unsigned short* __restrict__ Kraw,
    unsigned short* __restrict__ Vt)
{
  __shared__ unsigned short As[3][128 * 32];
  __shared__ unsigned short Bs[3][128 * 32];
  const int nt = blockIdx.x;               // 0..47
  const int n0 = nt * 128;
  const int m0 = blockIdx.y * 128;
  const int t = threadIdx.x, w = t >> 6, lane = t & 63;
  const int wm = w >> 1, wn = w & 1;
  const int mcol = lane & 15, quad = lane >> 4;
  const int lrow = lane >> 2, lcol = (lane & 3) * 8;   // staging map (16B/lane)

  const unsigned short* Ag = Xb + (size_t)m0 * HID;
  const unsigned short* Bg = Wb + (size_t)n0 * HID;

  f32x4 acc[4][4];
  #pragma unroll
  for (int i = 0; i < 4; i++)
    #pragma unroll
    for (int j = 0; j < 4; j++) acc[i][j] = (f32x4){0.f, 0.f, 0.f, 0.f};

  constexpr int NT = HID / 32;             // 128 K-tiles
  #define STAGE_QKV(buf, k0)                                                  \
    { const int c0 = w * 2, c1 = w * 2 + 1;                                   \
      gload_lds16(Ag + (size_t)(c0*16 + lrow) * HID + (k0) + lcol, &As[buf][c0 * 512]); \
      gload_lds16(Bg + (size_t)(c0*16 + lrow) * HID + (k0) + lcol, &Bs[buf][c0 * 512]); \
      gload_lds16(Ag + (size_t)(c1*16 + lrow) * HID + (k0) + lcol, &As[buf][c1 * 512]); \
      gload_lds16(Bg + (size_t)(c1*16 + lrow) * HID + (k0) + lcol, &Bs[buf][c1 * 512]); }

  STAGE_QKV(0, 0)
  STAGE_QKV(1, 32)
  asm volatile("s_waitcnt vmcnt(4)" ::: "memory");
  __builtin_amdgcn_s_barrier();
  __builtin_amdgcn_sched_barrier(0);

  int cur = 0, stg = 2;
  for (int kt = 0; kt < NT; ++kt) {
    if (kt + 2 < NT) STAGE_QKV(stg, (kt + 2) * 32)
    short8 af[4], bf[4];
    #pragma unroll
    for (int i = 0; i < 4; i++) af[i] = *(const short8*)&As[cur][(wm*64 + i*16 + mcol)*32 + quad*8];
    #pragma unroll
    for (int j = 0; j < 4; j++) bf[j] = *(const short8*)&Bs[cur][(wn*64 + j*16 + mcol)*32 + quad*8];
    #pragma unroll
    for (int i = 0; i < 4; i++)
      #pragma unroll
      for (int j = 0; j < 4; j++)
        acc[i][j] = __builtin_amdgcn_mfma_f32_16x16x32_bf16(af[i], bf[j], acc[i][j], 0, 0, 0);
    if (kt + 2 < NT) { asm volatile("s_waitcnt vmcnt(4)" ::: "memory"); }
    else             { asm volatile("s_waitcnt vmcnt(0)" ::: "memory"); }
    __builtin_amdgcn_s_barrier();
    __builtin_amdgcn_sched_barrier(0);
    cur = (cur == 2) ? 0 : cur + 1;
    stg = (stg == 2) ? 0 : stg + 1;
  }

  if (nt < 40) {
    unsigned short* dst = (nt < 32) ? (Qraw + (size_t)nt * HEAD_STRIDE)
                                    : (Kraw + (size_t)(nt - 32) * HEAD_STRIDE);
    #pragma unroll
    for (int i = 0; i < 4; i++) {
      const int rb = m0 + wm*64 + i*16 + quad*4;   // C/D: row=(lane>>4)*4+reg
      #pragma unroll
      for (int j = 0; j < 4; j++) {
        const int d = wn*64 + j*16 + mcol;         // col=lane&15
        #pragma unroll
        for (int r = 0; r < 4; r++)
          dst[(size_t)(rb + r) * HD + d] = f2bf(acc[i][j][r]);
      }
    }
  } else {
    unsigned short* dst = Vt + (size_t)(nt - 40) * HEAD_STRIDE;
    #pragma unroll
    for (int i = 0; i < 4; i++) {
      const int rb = m0 + wm*64 + i*16 + quad*4;   // 4 consecutive s per lane
      #pragma unroll
      for (int j = 0; j < 4; j++) {
        const int d = wn*64 + j*16 + mcol;
        ushort4 v4;
        v4.x = f2bf(acc[i][j][0]); v4.y = f2bf(acc[i][j][1]);
        v4.z = f2bf(acc[i][j][2]); v4.w = f2bf(acc[i][j][3]);
        *(ushort4*)(dst + (size_t)d * S_LEN + rb) = v4;
      }
    }
  }
}

// ---------------------------------------------------------------------------
// Kernel 2: RoPE in-place on bf16 Q and K. One wave per (head_row, s).
// ---------------------------------------------------------------------------
__global__ __launch_bounds__(256) void rope_qk_k(
    const int* __restrict__ pos_ids,
    unsigned short* __restrict__ Qraw, unsigned short* __restrict__ Kraw)
{
  const int w = threadIdx.x >> 6, lane = threadIdx.x & 63;
  const int gw = blockIdx.x * 4 + w;           // 0 .. (NH+NKV)*S-1
  const int hidx = gw >> 10;
  const int s = gw & 1023;
  const float pos = (float)pos_ids[s];
  const float invf = powf(10000.0f, -(float)lane * (1.0f / 64.0f));
  float sn, cs;
  sincosf(pos * invf, &sn, &cs);
  unsigned short* base = (hidx < NH)
      ? (Qraw + (size_t)hidx * HEAD_STRIDE + (size_t)s * HD)
      : (Kraw + (size_t)(hidx - NH) * HEAD_STRIDE + (size_t)s * HD);
  const float x0 = bf2f(base[lane]), x1 = bf2f(base[lane + 64]);
  base[lane]      = f2bf(x0 * cs - x1 * sn);
  base[lane + 64] = f2bf(x1 * cs + x0 * sn);
}

// ---------------------------------------------------------------------------
// Kernel 3: fused sparse attention, KT-specialized (KT = #128-key tiles).
//  Phase 2 select: 64-bin histogram (6 bits/pass, 3 passes) with 4 REPLICAS
//  (lane&3) to divide same-address atomic serialization by ~4 (clustered
//  score bins were the dominant SQ_LDS_BANK_CONFLICT source). Rows packed
//  pairwise in 16-bit fields; per-row early-exit guards stop atomics and
//  pass work once resolved (tot==krem). Remaining 14 bits via stateless
//  ballot refinement. Exact top-k, index-stable ties.
// ---------------------------------------------------------------------------
#define PSTR 1040
template<int KT>
__device__ __forceinline__ void attn_body(
    const unsigned short* __restrict__ Qb, const unsigned short* __restrict__ Kh,
    const unsigned short* __restrict__ Vh, unsigned short* __restrict__ AO,
    unsigned short (*Pl)[PSTR], unsigned (*hist)[256], float* rowinv,
    int q0, int h, int w, int lane, int mcol, int quad)
{
  constexpr int NC = 2 * KT;                   // 64-key chunks per row
  const float scale = 0.08838834764831845f;    // 1/sqrt(128)
  float (*scb)[16][130] = (float (*)[16][130])&Pl[0][0];  // 2x8320 B overlay

  short8 aq[4];
  {
    const unsigned short* qrow = Qb + ((size_t)h * S_LEN + q0 + mcol) * HD + quad * 8;
    #pragma unroll
    for (int kk = 0; kk < 4; kk++) aq[kk] = *(const short8*)(qrow + kk * 32);
  }

  unsigned su[4][NC];                          // wave-owned rows w*4..w*4+3

  // ---- Phase 1: scores -> dbuf chunk transpose -> registers ----
  #pragma unroll
  for (int kt = 0; kt < KT; kt++) {
    short8 bfr[2][4];
    #pragma unroll
    for (int g2 = 0; g2 < 2; g2++) {
      const int key = kt * 128 + (w * 2 + g2) * 16 + mcol;
      const unsigned short* krow = Kh + (size_t)key * HD + quad * 8;
      #pragma unroll
      for (int kk = 0; kk < 4; kk++) bfr[g2][kk] = *(const short8*)(krow + kk * 32);
    }
    f32x4 d4[2];
    d4[0] = (f32x4){0.f,0.f,0.f,0.f}; d4[1] = (f32x4){0.f,0.f,0.f,0.f};
    #pragma unroll
    for (int g2 = 0; g2 < 2; g2++)
      #pragma unroll
      for (int kk = 0; kk < 4; kk++)
        d4[g2] = __builtin_amdgcn_mfma_f32_16x16x32_bf16(aq[kk], bfr[g2][kk], d4[g2], 0, 0, 0);
    #pragma unroll
    for (int g2 = 0; g2 < 2; g2++) {
      const int colc = (w * 2 + g2) * 16 + mcol;
      #pragma unroll
      for (int r = 0; r < 4; r++) scb[kt & 1][quad*4 + r][colc] = d4[g2][r] * scale;
    }
    __syncthreads();
    #pragma unroll
    for (int i = 0; i < 4; i++)
      #pragma unroll
      for (int sub = 0; sub < 2; sub++)
        su[i][kt*2 + sub] = ordf(scb[kt & 1][w*4 + i][sub*64 + lane]);
  }
  __syncthreads();                             // scb dead; Pl overlay safe

  // ---- Phase 2: replicated 64-bin radix select + softmax ----
  const unsigned long long lmlt = (1ull << lane) - 1ull;
  const int rep = lane & 3;
  int Lr[4], krem[4], tot[4];
  unsigned prefix[4], pmsk[4];
  #pragma unroll
  for (int i = 0; i < 4; i++) {
    Lr[i] = q0 + w*4 + i + 1;
    int ks = Lr[i] >> 1; if (ks < 1) ks = 1;
    krem[i] = ks; tot[i] = Lr[i]; prefix[i] = 0u; pmsk[i] = 0u;
  }

  #pragma unroll
  for (int pass = 0; pass < 3; pass++) {
    const int shift = 26 - pass * 6;
    #pragma unroll
    for (int p = 0; p < 2; p++) {              // row pair: rows p*2, p*2+1
      const int i0 = p*2, i1 = p*2 + 1;
      if (tot[i0] <= krem[i0] && tot[i1] <= krem[i1]) continue;  // both done
      { uint4 z = {0u, 0u, 0u, 0u}; *(uint4*)&hist[w][lane * 4] = z; }
      wave_lds_fence();
      #pragma unroll
      for (int c = 0; c < NC; c++) {
        const int j = c * 64 + lane;
        #pragma unroll
        for (int rr = 0; rr < 2; rr++) {
          const int i = p * 2 + rr;
          if (tot[i] > krem[i] && j < Lr[i] && (su[i][c] & pmsk[i]) == prefix[i])
            atomicAdd(&hist[w][((su[i][c] >> shift) & 63) * 4 + rep], 1u << (16 * rr));
        }
      }
      wave_lds_fence();
      // merge replicas + packed descending scan (1 bin/lane, bin = 63-lane)
      const uint4 cv = *(const uint4*)&hist[w][(63 - lane) * 4];
      const unsigned cnt2 = cv.x + cv.y + cv.z + cv.w;  // 2 rows packed 16b
      unsigned x = cnt2;
      #pragma unroll
      for (int d2 = 1; d2 < 64; d2 <<= 1) { unsigned y = __shfl_up(x, d2); if (lane >= d2) x += y; }
      const unsigned runp = x - cnt2;            // count in bins above mine
      #pragma unroll
      for (int rr = 0; rr < 2; rr++) {
        const int i = p * 2 + rr;
        if (tot[i] <= krem[i]) continue;         // wave-uniform
        const int sh16 = 16 * rr;
        const int run = (int)((runp >> sh16) & 0xFFFFu);
        const int cn  = (int)((cnt2 >> sh16) & 0xFFFFu);
        const bool hit = (run < krem[i]) && (run + cn >= krem[i]);
        // pack bin(6b)<<22 | before(11b)<<11 | cnt(11b); one broadcast shfl
        unsigned packv = hit ? (((unsigned)(63 - lane) << 22) |
                                ((unsigned)run << 11) | (unsigned)cn) : 0u;
        const unsigned long long bal = __ballot(hit);
        const int srcl = __ffsll(bal) - 1;       // bal != 0 (row unresolved)
        const unsigned res = __shfl(packv, srcl);
        const int bin = res >> 22;
        const int before = (res >> 11) & 0x7FF;
        const int cn2 = res & 0x7FF;
        krem[i] -= before;
        tot[i] = cn2;
        prefix[i] |= ((unsigned)bin) << shift;
        pmsk[i] |= 63u << shift;
      }
    }
  }

  // ---- per-row residual refinement + fused exp/write sweep ----
  #pragma unroll
  for (int i = 0; i < 4; i++) {
    const int r = w * 4 + i;
    const int L = Lr[i];
    unsigned btau = prefix[i];
    unsigned bmsk = pmsk[i];
    int kr = krem[i];
    int tt = tot[i];
    const int bs = (bmsk == 0u) ? 31 : (__builtin_ctz(bmsk) - 1);
    // stateless bit-serial refinement of remaining bits (usually 0-2 iters)
    #pragma unroll 1
    for (int b = bs; b >= 0; --b) {
      if (tt <= kr) break;
      const unsigned bit = 1u << b;
      const unsigned am = bmsk | bit;
      const unsigned test = btau | bit;
      int cnt = 0;
      #pragma unroll
      for (int c = 0; c < NC; c++) {
        const int j = c * 64 + lane;
        cnt += (int)__popcll(__ballot(j < L && (su[i][c] & am) == test));
      }
      if (cnt >= kr) { btau = test; tt = cnt; }
      else           { kr -= cnt; tt -= cnt; }
      bmsk = am;
    }

    // mx = max over kept = row max (rank-1 element always kept)
    unsigned um = 0;
    #pragma unroll
    for (int c = 0; c < NC; c++) {
      const int j = c * 64 + lane;
      if (j < L && su[i][c] > um) um = su[i][c];
    }
    const float mx = iordf(wave_max_u(um));

    // fused: keep + exp + unnormalized-P write + sum
    float ssum = 0.f;
    int tiebase = 0;
    #pragma unroll
    for (int c = 0; c < NC; c++) {
      const int j = c * 64 + lane;
      const unsigned u = su[i][c];
      const unsigned umv = u & bmsk;
      const bool eq = (j < L) && (umv == btau);
      const unsigned long long bal = __ballot(eq);
      const int trank = tiebase + (int)__popcll(bal & lmlt);
      tiebase += (int)__popcll(bal);
      const bool kept = (j < L) &&
          ((umv > btau) || (eq && trank < kr) || (j < MIN_IDX));
      const float e = kept ? __expf(iordf(u) - mx) : 0.f;
      Pl[r][c*64 + lane] = f2bf(e);
      ssum += e;
    }
    ssum = wave_sum_f(ssum);
    if (lane == 0) rowinv[r] = 1.f / fmaxf(ssum, 1e-30f);
  }
  __syncthreads();

  // ---- Phase 3: PV (bf16 A from Pl, V direct from global) ----
  f32x4 opv[2];
  opv[0] = (f32x4){0.f,0.f,0.f,0.f}; opv[1] = (f32x4){0.f,0.f,0.f,0.f};
  #pragma unroll
  for (int kt = 0; kt < KT; kt++) {
    #pragma unroll
    for (int kb = 0; kb < 4; kb++) {
      short8 af = *(const short8*)&Pl[mcol][kt*128 + kb*32 + quad*8];
      #pragma unroll
      for (int n2 = 0; n2 < 2; n2++) {
        const int d = (w*2 + n2) * 16 + mcol;
        short8 bfr = *(const short8*)(Vh + (size_t)d * S_LEN + kt*128 + kb*32 + quad*8);
        opv[n2] = __builtin_amdgcn_mfma_f32_16x16x32_bf16(af, bfr, opv[n2], 0, 0, 0);
      }
    }
  }
  #pragma unroll
  for (int n2 = 0; n2 < 2; n2++) {
    const int col = h * HD + (w*2 + n2) * 16 + mcol;
    #pragma unroll
    for (int r2 = 0; r2 < 4; r2++) {
      const int row = q0 + quad*4 + r2;
      AO[(size_t)row * AO_COLS + col] = f2bf(opv[n2][r2] * rowinv[quad*4 + r2]);
    }
  }
}

__global__ __launch_bounds__(256, 4) void attn_k(
    const unsigned short* __restrict__ Qb, const unsigned short* __restrict__ Kb,
    const unsigned short* __restrict__ Vt, unsigned short* __restrict__ AO)
{
  __shared__ unsigned short Pl[16][PSTR];      // 33280 B
  __shared__ unsigned hist[4][256];            // 4096 B (64 bins x 4 replicas)
  __shared__ float rowinv[16];
  const int rb = (int)gridDim.x - 1 - (int)blockIdx.x;  // heavy blocks first
  const int h = blockIdx.y;
  const int kvh = h >> 2;                      // GROUPS=4
  const int q0 = rb * 16;
  const int kt_max = (rb >> 3) + 1;            // == (q0+16+127)>>7
  const int t = threadIdx.x, w = t >> 6, lane = t & 63;
  const int mcol = lane & 15, quad = lane >> 4;
  const unsigned short* Kh = Kb + (size_t)kvh * HEAD_STRIDE;  // [s][d]
  const unsigned short* Vh = Vt + (size_t)kvh * HEAD_STRIDE;  // [d][s]

  switch (kt_max) {
    case 1: attn_body<1>(Qb, Kh, Vh, AO, Pl, hist, rowinv, q0, h, w, lane, mcol, quad); break;
    case 2: attn_body<2>(Qb, Kh, Vh, AO, Pl, hist, rowinv, q0, h, w, lane, mcol, quad); break;
    case 3: attn_body<3>(Qb, Kh, Vh, AO, Pl, hist, rowinv, q0, h, w, lane, mcol, quad); break;
    case 4: attn_body<4>(Qb, Kh, Vh, AO, Pl, hist, rowinv, q0, h, w, lane, mcol, quad); break;
    case 5: attn_body<5>(Qb, Kh, Vh, AO, Pl, hist, rowinv, q0, h, w, lane, mcol, quad); break;
    case 6: attn_body<6>(Qb, Kh, Vh, AO, Pl, hist, rowinv, q0, h, w, lane, mcol, quad); break;
    case 7: attn_body<7>(Qb, Kh, Vh, AO, Pl, hist, rowinv, q0, h, w, lane, mcol, quad); break;
    default: attn_body<8>(Qb, Kh, Vh, AO, Pl, hist, rowinv, q0, h, w, lane, mcol, quad); break;
  }
}

// ---------------------------------------------------------------------------
// Kernel 4: output projection — same depth-2 counted-vmcnt pipeline.
// ---------------------------------------------------------------------------
__global__ __launch_bounds__(256) void gemm_out_k(
    const unsigned short* __restrict__ A, const unsigned short* __restrict__ Wob,
    float* __restrict__ Out)
{
  __shared__ unsigned short As[3][128 * 32];
  __shared__ unsigned short Bs[3][128 * 32];
  const int n0 = blockIdx.x * 128;
  const int m0 = blockIdx.y * 128;
  const int t = threadIdx.x, w = t >> 6, lane = t & 63;
  const int wm = w >> 1, wn = w & 1;
  const int mcol = lane & 15, quad = lane >> 4;
  const int lrow = lane >> 2, lcol = (lane & 3) * 8;

  const unsigned short* Ag = A   + (size_t)m0 * AO_COLS;
  const unsigned short* Bg = Wob + (size_t)n0 * AO_COLS;

  f32x4 acc[4][4];
  #pragma unroll
  for (int i = 0; i < 4; i++)
    #pragma unroll
    for (int j = 0; j < 4; j++) acc[i][j] = (f32x4){0.f, 0.f, 0.f, 0.f};

  constexpr int NT = AO_COLS / 32;         // 128 K-tiles
  #define STAGE_OUT(buf, k0)                                                  \
    { const int c0 = w * 2, c1 = w * 2 + 1;                                   \
      gload_lds16(Ag + (size_t)(c0*16 + lrow) * AO_COLS + (k0) + lcol, &As[buf][c0 * 512]); \
      gload_lds16(Bg + (size_t)(c0*16 + lrow) * AO_COLS + (k0) + lcol, &Bs[buf][c0 * 512]); \
      gload_lds16(Ag + (size_t)(c1*16 + lrow) * AO_COLS + (k0) + lcol, &As[buf][c1 * 512]); \
      gload_lds16(Bg + (size_t)(c1*16 + lrow) * AO_COLS + (k0) + lcol, &Bs[buf][c1 * 512]); }

  STAGE_OUT(0, 0)
  STAGE_OUT(1, 32)
  asm volatile("s_waitcnt vmcnt(4)" ::: "memory");
  __builtin_amdgcn_s_barrier();
  __builtin_amdgcn_sched_barrier(0);

  int cur = 0, stg = 2;
  for (int kt = 0; kt < NT; ++kt) {
    if (kt + 2 < NT) STAGE_OUT(stg, (kt + 2) * 32)
    short8 af[4], bf[4];
    #pragma unroll
    for (int i = 0; i < 4; i++) af[i] = *(const short8*)&As[cur][(wm*64 + i*16 + mcol)*32 + quad*8];
    #pragma unroll
    for (int j = 0; j < 4; j++) bf[j] = *(const short8*)&Bs[cur][(wn*64 + j*16 + mcol)*32 + quad*8];
    #pragma unroll
    for (int i = 0; i < 4; i++)
      #pragma unroll
      for (int j = 0; j < 4; j++)
        acc[i][j] = __builtin_amdgcn_mfma_f32_16x16x32_bf16(af[i], bf[j], acc[i][j], 0, 0, 0);
    if (kt + 2 < NT) { asm volatile("s_waitcnt vmcnt(4)" ::: "memory"); }
    else             { asm volatile("s_waitcnt vmcnt(0)" ::: "memory"); }
    __builtin_amdgcn_s_barrier();
    __builtin_amdgcn_sched_barrier(0);
    cur = (cur == 2) ? 0 : cur + 1;
    stg = (stg == 2) ? 0 : stg + 1;
  }

  #pragma unroll
  for (int i = 0; i < 4; i++) {
    const int rb = m0 + wm*64 + i*16 + quad*4;
    #pragma unroll
    for (int j = 0; j < 4; j++) {
      const int col = n0 + wn*64 + j*16 + mcol;
      #pragma unroll
      for (int r = 0; r < 4; r++)
        Out[(size_t)(rb + r) * HID + col] = acc[i][j][r];
    }
  }
}

// ---------------------------------------------------------------------------
// Workspace layout (79,691,776 bytes total):
//   [0)          Qraw  bf16 [NH][S][HD]          8,388,608
//   [+8388608)   Kraw  bf16 [NKV][S][HD]         2,097,152
//   [+10485760)  Vt    bf16 [NKV][HD][S]         2,097,152
//   [+12582912)  AO    bf16 [S][NH*HD]           8,388,608
//   [+20971520)  Xb    bf16 [S][HID]             8,388,608
//   [+29360128)  Wqkvb bf16 [6144][4096]        50,331,648
//                Wob   bf16 [4096][4096] aliases Wqkvb (cvt after gemm_qkv)
// ---------------------------------------------------------------------------
extern "C" void kernel_launch(void* const* d_in, const int* in_sizes, int n_in,
                              void* d_out, int out_size, void* d_ws, size_t ws_size,
                              hipStream_t stream) {
  (void)in_sizes; (void)n_in; (void)out_size; (void)ws_size;
  const float* X   = (const float*)d_in[0];
  const int*   pos = (const int*)d_in[1];
  const float* Wq  = (const float*)d_in[2];
  const float* Wk  = (const float*)d_in[3];
  const float* Wv  = (const float*)d_in[4];
  const float* Wo  = (const float*)d_in[5];
  float* out = (float*)d_out;

  char* ws = (char*)d_ws;
  unsigned short* Qraw  = (unsigned short*)ws;
  unsigned short* Kraw  = (unsigned short*)(ws + 8388608);
  unsigned short* Vt    = (unsigned short*)(ws + 10485760);
  unsigned short* AO    = (unsigned short*)(ws + 12582912);
  unsigned short* Xb    = (unsigned short*)(ws + 20971520);
  unsigned short* Wqkvb = (unsigned short*)(ws + 29360128);
  unsigned short* Wob   = Wqkvb;   // alias: Wo converted after gemm_qkv reads Wqkvb

  // bf16 conversions: X, Wq, Wk, Wv fused into one launch
  cvt4_k<<<dim3(14336), dim3(256), 0, stream>>>(X, Wq, Wk, Wv, Xb, Wqkvb);

  gemm_qkv_k<<<dim3(48, 8),  dim3(256), 0, stream>>>(Xb, Wqkvb, Qraw, Kraw, Vt);
  rope_qk_k <<<dim3(10240),  dim3(256), 0, stream>>>(pos, Qraw, Kraw);

  cvt_k<<<dim3(8192), dim3(256), 0, stream>>>(Wo, Wob);                      // 16.8M

  attn_k    <<<dim3(64, 32), dim3(256), 0, stream>>>(Qraw, Kraw, Vt, AO);
  gemm_out_k<<<dim3(32, 8),  dim3(256), 0, stream>>>(AO, Wob, out);
}